// Round 6
// baseline (91.401 us; speedup 1.0000x reference)
//
#include <hip/hip_runtime.h>

// TauLoss: 1 - mean_c [ sum_{i,j} sign(y[c,i]-y[c,j]) * tanh(p[c,i]-p[c,j]) / (N*(N-1)) ]
//
// R6 reformulation: per column, SORT (y, t=tanh(p)) by y ascending (fused
// in-LDS bitonic). In sorted order sgn(y_a - y_b) = +1 for a > b, so
//   sum_{i!=j} sgn*tanh = 2 * sum_{a>b} (t_a - t_b) / (1 - t_a*t_b)
// -- the sign math vanishes from the O(N^2) loop entirely, and the inner
// loop is pk_sub + pk_fma + rcp + pk_fma per pair (1.5 VALU + 1 trans).
// LDS traffic halves (t only): one b128 read feeds 4 j x 4 reg-held i = 16 pairs.
//
// R5 lesson: kernel ~23.7us (= total - 53.4us fixed harness floor: the 256MB
// d_ws re-poison fill at ~40us dominates rocprof top-5 permanently) vs ~6us
// issue floor. R6 cuts VALU/pair 5.5 -> 1.5, adds ~3-4us of sort.
//
// Grid: 512 blocks x 1024 thr (2 blocks/CU, 32 waves/CU) so one block's 55
// sort barriers / trans stalls hide behind the other block's issue.
// Diagonal tiles (a,b in same tile) use a masked scalar path (strict a>b);
// off-diag tiles (ti > tj) are unmasked weight-1.

typedef float v2f __attribute__((ext_vector_type(2)));

#define TAU_N 1024
#define TAU_C 128
#define TILE  128
#define NTILE (TAU_N / TILE)              // 8
#define NTP   (NTILE * (NTILE + 1) / 2)   // 36 tile-pairs (ti >= tj) per column
#define BPC   4                           // blocks per column
#define JOBS  (NTP / BPC)                 // 9 jobs per block
#define PBLK  (TAU_C * BPC)               // 512 blocks
#define THR   1024                        // 16 waves per block

__device__ __constant__ unsigned char c_TI[NTP] = {
    0,1,1,2,2,2,3,3,3,3,4,4,4,4,4,5,5,5,5,5,5,
    6,6,6,6,6,6,6,7,7,7,7,7,7,7,7};
__device__ __constant__ unsigned char c_TJ[NTP] = {
    0,0,1,0,1,2,0,1,2,3,0,1,2,3,4,0,1,2,3,4,5,
    0,1,2,3,4,5,6,0,1,2,3,4,5,6,7};

__global__ __launch_bounds__(THR, 8) void tau_sorted_kernel(
        const float* __restrict__ pred, const float* __restrict__ y,
        float* __restrict__ out, float* __restrict__ acc_ws,
        unsigned* __restrict__ cnt_ws) {
    __shared__ __align__(16) float2 kv[TAU_N];   // sort buffer: (y, tanh(p))
    __shared__ float wsum[THR / 64];
    float* ts = (float*)kv;                      // sorted t, aliased over kv

    const int bx  = blockIdx.x;
    const int tid = threadIdx.x;
    const int c   = bx >> 2;                     // bx / BPC
    const int jb0 = (bx & (BPC - 1)) * JOBS;

    const float* p = pred + c * TAU_N;
    const float* l = y    + c * TAU_N;

    // ---- Phase 1: load + tanh + bitonic sort by y ascending ----
    kv[tid] = make_float2(l[tid], tanhf(p[tid]));
    __syncthreads();

    for (int k = 2; k <= TAU_N; k <<= 1) {
        for (int j = k >> 1; j > 0; j >>= 1) {
            const int ixj = tid ^ j;
            if (ixj > tid) {
                float2 a  = kv[tid];
                float2 b2 = kv[ixj];
                const bool up = ((tid & k) == 0);
                if ((a.x > b2.x) == up) { kv[tid] = b2; kv[ixj] = a; }
            }
            __syncthreads();
        }
    }

    // Compact sorted t into a flat float array (aliased; barrier-protected).
    const float tv = kv[tid].y;
    __syncthreads();
    ts[tid] = tv;
    __syncthreads();

    // ---- Phase 2: triangular tile-pair jobs, sign-free ----
    const float4* ts4 = (const float4*)ts;
    const int ig = tid >> 5;                     // 32 i-groups (4 i each)
    const int js = tid & 31;                     // 32 j-slices (4 j each)
    const v2f one2 = {1.f, 1.f};

    v2f accA = {0.f, 0.f}, accB = {0.f, 0.f};
    float acc_s = 0.f;

    for (int q = 0; q < JOBS; ++q) {
        const int job = jb0 + q;
        const int ti  = c_TI[job];
        const int tj  = c_TJ[job];
        const float4 mt4 = ts4[ti * (TILE / 4) + ig];   // my 4 i t-values
        const float4 tq  = ts4[tj * (TILE / 4) + js];   // my 4 j t-values
        if (ti != tj) {
            // Off-diag: every (a,b) has a>b; weight 1, packed math.
            const v2f t01 = {tq.x, tq.y};
            const v2f t23 = {tq.z, tq.w};
            const float mts[4] = {mt4.x, mt4.y, mt4.z, mt4.w};
#pragma unroll
            for (int a = 0; a < 4; ++a) {
                const v2f m2 = {mts[a], mts[a]};
                v2f n01 = m2 - t01;
                v2f n23 = m2 - t23;
                v2f d01 = __builtin_elementwise_fma(-m2, t01, one2);
                v2f d23 = __builtin_elementwise_fma(-m2, t23, one2);
                v2f r01 = {__builtin_amdgcn_rcpf(d01.x),
                           __builtin_amdgcn_rcpf(d01.y)};
                v2f r23 = {__builtin_amdgcn_rcpf(d23.x),
                           __builtin_amdgcn_rcpf(d23.y)};
                accA = __builtin_elementwise_fma(n01, r01, accA);
                accB = __builtin_elementwise_fma(n23, r23, accB);
            }
        } else {
            // Diag tile: strict a>b mask (antisymmetric summand would cancel).
            const int gib = ig * 4, gjb = js * 4;
            const float mts[4] = {mt4.x, mt4.y, mt4.z, mt4.w};
            const float tjs[4] = {tq.x, tq.y, tq.z, tq.w};
#pragma unroll
            for (int a = 0; a < 4; ++a) {
#pragma unroll
                for (int b = 0; b < 4; ++b) {
                    float n = mts[a] - tjs[b];
                    float d = __builtin_fmaf(-mts[a], tjs[b], 1.f);
                    float v = n * __builtin_amdgcn_rcpf(d);
                    acc_s += (gib + a > gjb + b) ? v : 0.f;
                }
            }
        }
    }
    float acc = (accA.x + accA.y) + (accB.x + accB.y) + acc_s;

    // ---- Reduce: wave shuffle -> LDS -> one atomic per block ----
    for (int off = 32; off >= 1; off >>= 1)
        acc += __shfl_down(acc, off, 64);
    if ((tid & 63) == 0) wsum[tid >> 6] = acc;
    __syncthreads();
    if (tid == 0) {
        float t = 0.f;
#pragma unroll
        for (int w = 0; w < THR / 64; ++w) t += wsum[w];
        atomicAdd(acc_ws, t);
        __threadfence();
        unsigned old = atomicAdd(cnt_ws, 1u);
        if (old == PBLK - 1) {               // last block: all adds visible
            __threadfence();
            float total = atomicAdd(acc_ws, 0.0f);
            const float scale = 2.0f / ((float)TAU_N * (float)(TAU_N - 1) * (float)TAU_C);
            out[0] = 1.0f - total * scale;
        }
    }
}

extern "C" void kernel_launch(void* const* d_in, const int* in_sizes, int n_in,
                              void* d_out, int out_size, void* d_ws, size_t ws_size,
                              hipStream_t stream) {
    const float* pred = (const float*)d_in[0];
    const float* y    = (const float*)d_in[1];
    float* out        = (float*)d_out;
    float* acc_ws     = (float*)d_ws;
    unsigned* cnt_ws  = (unsigned*)d_ws + 1;

    hipMemsetAsync(d_ws, 0, 2 * sizeof(unsigned), stream);  // zero acc + counter
    tau_sorted_kernel<<<PBLK, THR, 0, stream>>>(pred, y, out, acc_ws, cnt_ws);
}

// Round 7
// 80.558 us; speedup vs baseline: 1.1346x; 1.1346x over previous
//
#include <hip/hip_runtime.h>

// TauLoss: 1 - mean_c [ sum_{i,j} sign(y[c,i]-y[c,j]) * tanh(p[c,i]-p[c,j]) / (N*(N-1)) ]
//
// Identities:
//   tanh(d*s) = s*tanh(d), s in {-1,0,1}
//   tanh(a-b) = (ta-tb)/(1-ta*tb)   -> tanh once per element, not per pair
//   summand symmetric under i<->j   -> 2 * sum over unordered tri tile-pairs
//   s*val = val ^ signbit(l_i-l_j)  -> exact except y-ties (error <1e-7 on output)
//
// History: R5 (sign-xor, 1 block/CU, AoS float2 LDS) kernel ~23.7us.
// R6 (in-kernel bitonic sort to kill sign) REGRESSED to 42us: 2.4M LDS bank
// conflict cycles + 55 barrier-serialized divergent stages. Sort is dead.
// Fixed harness overhead in dur_us ~50us (256MB d_ws re-poison fill ~40us
// + input restores); kernel time = total - ~50.
//
// R7 = R5 skeleton with stall fixes:
//  - 768 blocks x 512 thr (3 blocks/CU, 24 waves/CU) -> INDEPENDENT blocks
//    hide each other's barriers and LDS latency.
//  - SoA LDS (ts/ys) + IT=8 i-fragments in registers: one 4-j read pair
//    (2x ds_read_b128) feeds 32 pairs (~290 cyc math) -> LDS latency moot.
//  - Uniform 6 jobs/block over TILE=128 triangular tile-pairs; diag jobs run
//    the full tile at weight 0.5 (diagonal contributes exactly 0) -> no
//    divergence, no masking; straight-line 32-pair body, 4 rotating accs.
// Issue floor ~4.8us (VALU 18cyc / 2 pairs / wave co-issued with 2x rcp on
// the trans pipe); predict kernel 9-13us.

typedef float v2f __attribute__((ext_vector_type(2)));

#define TAU_N 1024
#define TAU_C 128
#define TILE  128
#define NTILE (TAU_N / TILE)              // 8
#define NTP   (NTILE * (NTILE + 1) / 2)   // 36 tile-pairs (ti >= tj) per column
#define BPC   6                           // blocks per column
#define JOBS  (NTP / BPC)                 // 6 jobs per block
#define PBLK  (TAU_C * BPC)               // 768 blocks (3 per CU)
#define THR   512                         // 8 waves per block
#define IT    8                           // i-elements per thread (registers)

__device__ __constant__ unsigned char c_TI[NTP] = {
    0,1,1,2,2,2,3,3,3,3,4,4,4,4,4,5,5,5,5,5,5,
    6,6,6,6,6,6,6,7,7,7,7,7,7,7,7};
__device__ __constant__ unsigned char c_TJ[NTP] = {
    0,0,1,0,1,2,0,1,2,3,0,1,2,3,4,0,1,2,3,4,5,
    0,1,2,3,4,5,6,0,1,2,3,4,5,6,7};

__device__ __forceinline__ v2f tau_group(v2f m2, v2f mly, v2f t2, v2f l2, v2f acc) {
    const v2f one2 = {1.f, 1.f};
    v2f n  = m2 - t2;                                   // pk_sub
    v2f d  = __builtin_elementwise_fma(-m2, t2, one2);  // pk_fma: 1 - mt*tj
    v2f r  = {__builtin_amdgcn_rcpf(d.x), __builtin_amdgcn_rcpf(d.y)};
    v2f v  = n * r;                                     // pk_mul: tanh(pi-pj)
    v2f ld = mly - l2;                                  // pk_sub
    v2f sv = {__uint_as_float(__float_as_uint(v.x) ^
                              (__float_as_uint(ld.x) & 0x80000000u)),
              __uint_as_float(__float_as_uint(v.y) ^
                              (__float_as_uint(ld.y) & 0x80000000u))};
    return acc + sv;                                    // pk_add
}

__global__ __launch_bounds__(THR, 6) void tau_tri_kernel(
        const float* __restrict__ pred, const float* __restrict__ y,
        float* __restrict__ out, float* __restrict__ acc_ws,
        unsigned* __restrict__ cnt_ws) {
    __shared__ __align__(16) float ts[TAU_N];   // tanh(p), SoA
    __shared__ __align__(16) float ys[TAU_N];   // y, SoA
    __shared__ float wsum[THR / 64];

    const int bx  = blockIdx.x;
    const int tid = threadIdx.x;
    const int c   = bx / BPC;
    const int jb0 = (bx % BPC) * JOBS;

    const float* p = pred + c * TAU_N;
    const float* l = y    + c * TAU_N;

    // Stage column (SoA): 2 elements per thread, one barrier.
    ts[tid]       = tanhf(p[tid]);
    ts[tid + THR] = tanhf(p[tid + THR]);
    ys[tid]       = l[tid];
    ys[tid + THR] = l[tid + THR];
    __syncthreads();

    const float4* t4 = (const float4*)ts;
    const float4* y4 = (const float4*)ys;
    const int ig = tid >> 5;          // 16 i-groups of IT=8
    const int js = tid & 31;          // 32 j-slices of 4

    float acc_tot = 0.f;

#pragma unroll
    for (int q = 0; q < JOBS; ++q) {
        const int job = jb0 + q;
        const int ti  = c_TI[job];
        const int tj  = c_TJ[job];

        // i-fragments: 8 t's + 8 y's from LDS (broadcast reads, 4x b128).
        const int ib4 = (ti * TILE + ig * IT) >> 2;
        const float4 ta = t4[ib4], tb = t4[ib4 + 1];
        const float4 la = y4[ib4], lb = y4[ib4 + 1];
        const float mt[IT] = {ta.x, ta.y, ta.z, ta.w, tb.x, tb.y, tb.z, tb.w};
        const float ml[IT] = {la.x, la.y, la.z, la.w, lb.x, lb.y, lb.z, lb.w};

        // j-slice: 4 j's (2x b128), feeds 32 pairs.
        const int jb4 = (tj * TILE + js * 4) >> 2;
        const float4 tj4 = t4[jb4];
        const float4 yj4 = y4[jb4];
        const v2f tA = {tj4.x, tj4.y}, tB = {tj4.z, tj4.w};
        const v2f lA = {yj4.x, yj4.y}, lB = {yj4.z, yj4.w};

        v2f a0 = {0.f,0.f}, a1 = {0.f,0.f}, a2 = {0.f,0.f}, a3 = {0.f,0.f};
#pragma unroll
        for (int a = 0; a < IT; ++a) {
            const v2f m2  = {mt[a], mt[a]};
            const v2f mly = {ml[a], ml[a]};
            if (a & 1) {
                a1 = tau_group(m2, mly, tA, lA, a1);
                a3 = tau_group(m2, mly, tB, lB, a3);
            } else {
                a0 = tau_group(m2, mly, tA, lA, a0);
                a2 = tau_group(m2, mly, tB, lB, a2);
            }
        }
        const v2f asum = (a0 + a1) + (a2 + a3);
        const float s = asum.x + asum.y;
        // Diag tiles cover each unordered pair twice (i==j contributes 0).
        acc_tot += (ti == tj) ? 0.5f * s : s;
    }

    // Wave reduce, cross-wave via LDS, one atomic per block.
    for (int off = 32; off >= 1; off >>= 1)
        acc_tot += __shfl_down(acc_tot, off, 64);
    if ((tid & 63) == 0) wsum[tid >> 6] = acc_tot;
    __syncthreads();
    if (tid == 0) {
        float t = 0.f;
#pragma unroll
        for (int w = 0; w < THR / 64; ++w) t += wsum[w];
        atomicAdd(acc_ws, t);
        __threadfence();
        unsigned old = atomicAdd(cnt_ws, 1u);
        if (old == PBLK - 1) {            // last block: all adds visible
            __threadfence();
            float total = atomicAdd(acc_ws, 0.0f);
            const float scale = 2.0f / ((float)TAU_N * (float)(TAU_N - 1) * (float)TAU_C);
            out[0] = 1.0f - total * scale;
        }
    }
}

extern "C" void kernel_launch(void* const* d_in, const int* in_sizes, int n_in,
                              void* d_out, int out_size, void* d_ws, size_t ws_size,
                              hipStream_t stream) {
    const float* pred = (const float*)d_in[0];
    const float* y    = (const float*)d_in[1];
    float* out        = (float*)d_out;
    float* acc_ws     = (float*)d_ws;
    unsigned* cnt_ws  = (unsigned*)d_ws + 1;

    hipMemsetAsync(d_ws, 0, 2 * sizeof(unsigned), stream);  // zero acc + counter
    tau_tri_kernel<<<PBLK, THR, 0, stream>>>(pred, y, out, acc_ws, cnt_ws);
}

// Round 8
// 69.840 us; speedup vs baseline: 1.3087x; 1.1535x over previous
//
#include <hip/hip_runtime.h>

// TauLoss: 1 - mean_c [ sum_{i,j} sign(y[c,i]-y[c,j]) * tanh(p[c,i]-p[c,j]) / (N*(N-1)) ]
//
// Identities:
//   tanh(d*s) = s*tanh(d), s in {-1,0,1}
//   tanh(a-b) = (ta-tb)/(1-ta*tb), r = 1/(1-ta*tb) > 0  -> tanh once per element
//   summand symmetric under i<->j   -> 2 * sum over unordered tri tile-pairs
//   (n*r)^signbit == (n^signbit)*r  (r>0, exact)  -> sign folds into the fma
//
// History: R5 ~23.7us kernel / R7 ~27us (kernel = total - ~53us harness floor:
// the 256MB d_ws re-poison fill ~40us dominates rocprof top-5 permanently).
// R6 sort: dead (bank conflicts + barrier serialization). R7's better inner
// loop LOST to R5 because the single-address atomicAdd+threadfence tail scales
// with block count (768x2 serialized cross-XCD RMWs ~ 10-20us).
//
// R8: NO ATOMICS. Main kernel -> plain partials[bx] store; tiny finalize
// kernel reduces 512 floats (kernel-boundary ordering guarantees visibility).
// Grid 512 x 1024 (2 blocks/CU, 32 waves/CU, launch_bounds(1024,8) pins
// VGPR<=64). TILE=128, 9 jobs/block, IT=4 x 4j = 16 pairs/thread/job; sign
// folded into numerator before a single pk_fma accumulate.

typedef float v2f __attribute__((ext_vector_type(2)));

#define TAU_N 1024
#define TAU_C 128
#define TILE  128
#define NTILE (TAU_N / TILE)              // 8
#define NTP   (NTILE * (NTILE + 1) / 2)   // 36 tile-pairs (ti >= tj) per column
#define BPC   4                           // blocks per column
#define JOBS  (NTP / BPC)                 // 9 jobs per block
#define PBLK  (TAU_C * BPC)               // 512 blocks (2 per CU)
#define THR   1024                        // 16 waves per block
#define IT    4                           // i-elements per thread

__device__ __constant__ unsigned char c_TI[NTP] = {
    0,1,1,2,2,2,3,3,3,3,4,4,4,4,4,5,5,5,5,5,5,
    6,6,6,6,6,6,6,7,7,7,7,7,7,7,7};
__device__ __constant__ unsigned char c_TJ[NTP] = {
    0,0,1,0,1,2,0,1,2,3,0,1,2,3,4,0,1,2,3,4,5,
    0,1,2,3,4,5,6,0,1,2,3,4,5,6,7};
__device__ __constant__ float c_W[NTP] = {
    0.5f,1,0.5f,1,1,0.5f,1,1,1,0.5f,1,1,1,1,0.5f,1,1,1,1,1,0.5f,
    1,1,1,1,1,1,0.5f,1,1,1,1,1,1,1,0.5f};

// 2 pairs: n = mt - tj; d = 1 - mt*tj; ld = ml - lj;
// acc += (n ^ signbit(ld)) * rcp(d)   [exact: rcp>0]
__device__ __forceinline__ v2f tau_group(v2f m2, v2f mly, v2f t2, v2f l2, v2f acc) {
    const v2f one2 = {1.f, 1.f};
    v2f n  = m2 - t2;                                   // pk_sub
    v2f d  = __builtin_elementwise_fma(-m2, t2, one2);  // pk_fma
    v2f r  = {__builtin_amdgcn_rcpf(d.x), __builtin_amdgcn_rcpf(d.y)};
    v2f ld = mly - l2;                                  // pk_sub
    v2f ns = {__uint_as_float(__float_as_uint(n.x) ^
                              (__float_as_uint(ld.x) & 0x80000000u)),
              __uint_as_float(__float_as_uint(n.y) ^
                              (__float_as_uint(ld.y) & 0x80000000u))};
    return __builtin_elementwise_fma(ns, r, acc);       // pk_fma
}

__global__ __launch_bounds__(THR, 8) void tau_tri_kernel(
        const float* __restrict__ pred, const float* __restrict__ y,
        float* __restrict__ partials) {
    __shared__ __align__(16) float ts[TAU_N];   // tanh(p)
    __shared__ __align__(16) float ys[TAU_N];   // y
    __shared__ float wsum[THR / 64];

    const int bx  = blockIdx.x;
    const int tid = threadIdx.x;
    const int c   = bx >> 2;                    // bx / BPC
    const int jb0 = (bx & (BPC - 1)) * JOBS;

    const float* p = pred + c * TAU_N;
    const float* l = y    + c * TAU_N;

    // Stage column (SoA): 1 element per thread, one barrier.
    ts[tid] = tanhf(p[tid]);
    ys[tid] = l[tid];
    __syncthreads();

    const float4* t4 = (const float4*)ts;
    const float4* y4 = (const float4*)ys;
    const int ig = tid >> 5;                    // 32 i-groups of IT=4
    const int js = tid & 31;                    // 32 j-slices of 4 j

    float acc_tot = 0.f;

#pragma unroll
    for (int q = 0; q < JOBS; ++q) {
        const int job = jb0 + q;
        const int ti  = c_TI[job];
        const int tj  = c_TJ[job];
        const float w = c_W[job];

        const float4 mt4 = t4[ti * (TILE / 4) + ig];   // my 4 i t-values
        const float4 ml4 = y4[ti * (TILE / 4) + ig];   // my 4 i y-values
        const float4 tj4 = t4[tj * (TILE / 4) + js];   // my 4 j t-values
        const float4 yj4 = y4[tj * (TILE / 4) + js];   // my 4 j y-values

        const v2f tA = {tj4.x, tj4.y}, tB = {tj4.z, tj4.w};
        const v2f lA = {yj4.x, yj4.y}, lB = {yj4.z, yj4.w};
        const float mt[IT] = {mt4.x, mt4.y, mt4.z, mt4.w};
        const float ml[IT] = {ml4.x, ml4.y, ml4.z, ml4.w};

        v2f a0 = {0.f,0.f}, a1 = {0.f,0.f}, a2 = {0.f,0.f}, a3 = {0.f,0.f};
#pragma unroll
        for (int a = 0; a < IT; ++a) {
            const v2f m2  = {mt[a], mt[a]};
            const v2f mly = {ml[a], ml[a]};
            if (a & 1) {
                a1 = tau_group(m2, mly, tA, lA, a1);
                a3 = tau_group(m2, mly, tB, lB, a3);
            } else {
                a0 = tau_group(m2, mly, tA, lA, a0);
                a2 = tau_group(m2, mly, tB, lB, a2);
            }
        }
        const v2f asum = (a0 + a1) + (a2 + a3);
        acc_tot = __builtin_fmaf(w, asum.x + asum.y, acc_tot);
    }

    // Wave reduce -> cross-wave LDS -> ONE plain store per block. No atomics.
    for (int off = 32; off >= 1; off >>= 1)
        acc_tot += __shfl_down(acc_tot, off, 64);
    if ((tid & 63) == 0) wsum[tid >> 6] = acc_tot;
    __syncthreads();
    if (tid == 0) {
        float t = 0.f;
#pragma unroll
        for (int w = 0; w < THR / 64; ++w) t += wsum[w];
        partials[bx] = t;
    }
}

__global__ __launch_bounds__(PBLK) void tau_finalize_kernel(
        const float* __restrict__ partials, float* __restrict__ out) {
    __shared__ float wsum[PBLK / 64];
    const int tid = threadIdx.x;               // PBLK = 512 threads
    float acc = partials[tid];
    for (int off = 32; off >= 1; off >>= 1)
        acc += __shfl_down(acc, off, 64);
    if ((tid & 63) == 0) wsum[tid >> 6] = acc;
    __syncthreads();
    if (tid == 0) {
        float t = 0.f;
#pragma unroll
        for (int w = 0; w < PBLK / 64; ++w) t += wsum[w];
        const float scale = 2.0f / ((float)TAU_N * (float)(TAU_N - 1) * (float)TAU_C);
        out[0] = 1.0f - t * scale;
    }
}

extern "C" void kernel_launch(void* const* d_in, const int* in_sizes, int n_in,
                              void* d_out, int out_size, void* d_ws, size_t ws_size,
                              hipStream_t stream) {
    const float* pred = (const float*)d_in[0];
    const float* y    = (const float*)d_in[1];
    float* out        = (float*)d_out;
    float* partials   = (float*)d_ws;   // PBLK floats; each written exactly once

    tau_tri_kernel<<<PBLK, THR, 0, stream>>>(pred, y, partials);
    tau_finalize_kernel<<<1, PBLK, 0, stream>>>(partials, out);
}

// Round 9
// 69.009 us; speedup vs baseline: 1.3245x; 1.0120x over previous
//
#include <hip/hip_runtime.h>

// TauLoss: 1 - mean_c [ sum_{i,j} sign(y[c,i]-y[c,j]) * tanh(p[c,i]-p[c,j]) / (N*(N-1)) ]
//
// Identities:
//   tanh(d*s) = s*tanh(d), s in {-1,0,1}
//   tanh(a-b) = (ta-tb)/(1-ta*tb), r = 1/(1-ta*tb) > 0  -> tanh once per element
//   summand symmetric under i<->j   -> 2 * sum over unordered tri tile-pairs
//   (n*r)^signbit == (n^signbit)*r  (r>0, exact)  -> sign folds into the fma
//
// History: R8 (no atomics: plain partials store + tiny finalize kernel) total
// 69.8us = ~53us immovable harness floor (256MB d_ws poison fill ~40us etc.)
// + ~17us kernel-side. Atomic tail removal was worth ~11us (R7->R8).
// Issue floor for this inner loop ~5.8us (24 cyc VALU / 128 pairs, trans
// co-issued). R9 targets main-kernel stalls:
//  - 768 x 512 (3 blocks/CU): more independent blocks cover barriers + drain
//    tail faster (R7 grid, now without R7's atomics).
//  - IT=8 x JT=4 = 32 pairs/thread/job: halves job overhead vs math.
//  - explicit cross-job prefetch of the 6 LDS vectors.

typedef float v2f __attribute__((ext_vector_type(2)));

#define TAU_N 1024
#define TAU_C 128
#define TILE  128
#define NTILE (TAU_N / TILE)              // 8
#define NTP   (NTILE * (NTILE + 1) / 2)   // 36 tile-pairs (ti >= tj) per column
#define BPC   6                           // blocks per column
#define JOBS  (NTP / BPC)                 // 6 jobs per block
#define PBLK  (TAU_C * BPC)               // 768 blocks (3 per CU)
#define THR   512                         // 8 waves per block
#define IT    8                           // i-elements per thread

__device__ __constant__ unsigned char c_TI[NTP] = {
    0,1,1,2,2,2,3,3,3,3,4,4,4,4,4,5,5,5,5,5,5,
    6,6,6,6,6,6,6,7,7,7,7,7,7,7,7};
__device__ __constant__ unsigned char c_TJ[NTP] = {
    0,0,1,0,1,2,0,1,2,3,0,1,2,3,4,0,1,2,3,4,5,
    0,1,2,3,4,5,6,0,1,2,3,4,5,6,7};
__device__ __constant__ float c_W[NTP] = {
    0.5f,1,0.5f,1,1,0.5f,1,1,1,0.5f,1,1,1,1,0.5f,1,1,1,1,1,0.5f,
    1,1,1,1,1,1,0.5f,1,1,1,1,1,1,1,0.5f};

// 2 pairs: n = mt-tj; d = 1-mt*tj; ld = ml-lj; acc += (n^signbit(ld))*rcp(d)
__device__ __forceinline__ v2f tau_group(v2f m2, v2f mly, v2f t2, v2f l2, v2f acc) {
    const v2f one2 = {1.f, 1.f};
    v2f n  = m2 - t2;                                   // pk_sub
    v2f d  = __builtin_elementwise_fma(-m2, t2, one2);  // pk_fma
    v2f r  = {__builtin_amdgcn_rcpf(d.x), __builtin_amdgcn_rcpf(d.y)};
    v2f ld = mly - l2;                                  // pk_sub
    v2f ns = {__uint_as_float(__float_as_uint(n.x) ^
                              (__float_as_uint(ld.x) & 0x80000000u)),
              __uint_as_float(__float_as_uint(n.y) ^
                              (__float_as_uint(ld.y) & 0x80000000u))};
    return __builtin_elementwise_fma(ns, r, acc);       // pk_fma
}

__global__ __launch_bounds__(THR, 6) void tau_tri_kernel(
        const float* __restrict__ pred, const float* __restrict__ y,
        float* __restrict__ partials) {
    __shared__ __align__(16) float ts[TAU_N];   // tanh(p)
    __shared__ __align__(16) float ys[TAU_N];   // y
    __shared__ float wsum[THR / 64];

    const int bx  = blockIdx.x;
    const int tid = threadIdx.x;
    const int c   = bx / BPC;
    const int jb0 = (bx % BPC) * JOBS;

    const float* p = pred + c * TAU_N;
    const float* l = y    + c * TAU_N;

    // Stage column (SoA): 2 elements per thread, one barrier.
    ts[tid]       = tanhf(p[tid]);
    ts[tid + THR] = tanhf(p[tid + THR]);
    ys[tid]       = l[tid];
    ys[tid + THR] = l[tid + THR];
    __syncthreads();

    const float4* t4 = (const float4*)ts;
    const float4* y4 = (const float4*)ys;
    const int ig = tid >> 5;                    // 16 i-groups of IT=8
    const int js = tid & 31;                    // 32 j-slices of 4 j

    // Prefetched LDS vectors for job q: 2x i-t, 2x i-y, 1x j-t, 1x j-y.
    float4 ta, tb, la, lb, tj4, yj4;
    {
        const int ti0 = c_TI[jb0], tj0 = c_TJ[jb0];
        const int ib4 = (ti0 * TILE + ig * IT) >> 2;
        const int jb4 = (tj0 * TILE + js * 4) >> 2;
        ta = t4[ib4]; tb = t4[ib4 + 1];
        la = y4[ib4]; lb = y4[ib4 + 1];
        tj4 = t4[jb4]; yj4 = y4[jb4];
    }

    float acc_tot = 0.f;

#pragma unroll
    for (int q = 0; q < JOBS; ++q) {
        const float w = c_W[jb0 + q];
        const float4 cta = ta, ctb = tb, cla = la, clb = lb;
        const float4 ctj = tj4, cyj = yj4;

        if (q + 1 < JOBS) {                     // prefetch next job's vectors
            const int tin = c_TI[jb0 + q + 1], tjn = c_TJ[jb0 + q + 1];
            const int ib4 = (tin * TILE + ig * IT) >> 2;
            const int jb4 = (tjn * TILE + js * 4) >> 2;
            ta = t4[ib4]; tb = t4[ib4 + 1];
            la = y4[ib4]; lb = y4[ib4 + 1];
            tj4 = t4[jb4]; yj4 = y4[jb4];
        }

        const v2f tA = {ctj.x, ctj.y}, tB = {ctj.z, ctj.w};
        const v2f lA = {cyj.x, cyj.y}, lB = {cyj.z, cyj.w};
        const float mt[IT] = {cta.x, cta.y, cta.z, cta.w, ctb.x, ctb.y, ctb.z, ctb.w};
        const float ml[IT] = {cla.x, cla.y, cla.z, cla.w, clb.x, clb.y, clb.z, clb.w};

        v2f a0 = {0.f,0.f}, a1 = {0.f,0.f}, a2 = {0.f,0.f}, a3 = {0.f,0.f};
#pragma unroll
        for (int a = 0; a < IT; ++a) {
            const v2f m2  = {mt[a], mt[a]};
            const v2f mly = {ml[a], ml[a]};
            if (a & 1) {
                a1 = tau_group(m2, mly, tA, lA, a1);
                a3 = tau_group(m2, mly, tB, lB, a3);
            } else {
                a0 = tau_group(m2, mly, tA, lA, a0);
                a2 = tau_group(m2, mly, tB, lB, a2);
            }
        }
        const v2f asum = (a0 + a1) + (a2 + a3);
        acc_tot = __builtin_fmaf(w, asum.x + asum.y, acc_tot);
    }

    // Wave reduce -> cross-wave LDS -> ONE plain store per block. No atomics.
    for (int off = 32; off >= 1; off >>= 1)
        acc_tot += __shfl_down(acc_tot, off, 64);
    if ((tid & 63) == 0) wsum[tid >> 6] = acc_tot;
    __syncthreads();
    if (tid == 0) {
        float t = 0.f;
#pragma unroll
        for (int w = 0; w < THR / 64; ++w) t += wsum[w];
        partials[bx] = t;
    }
}

__global__ __launch_bounds__(PBLK) void tau_finalize_kernel(
        const float* __restrict__ partials, float* __restrict__ out) {
    __shared__ float wsum[PBLK / 64];
    const int tid = threadIdx.x;               // PBLK = 768 threads
    float acc = partials[tid];
    for (int off = 32; off >= 1; off >>= 1)
        acc += __shfl_down(acc, off, 64);
    if ((tid & 63) == 0) wsum[tid >> 6] = acc;
    __syncthreads();
    if (tid == 0) {
        float t = 0.f;
#pragma unroll
        for (int w = 0; w < PBLK / 64; ++w) t += wsum[w];
        const float scale = 2.0f / ((float)TAU_N * (float)(TAU_N - 1) * (float)TAU_C);
        out[0] = 1.0f - t * scale;
    }
}

extern "C" void kernel_launch(void* const* d_in, const int* in_sizes, int n_in,
                              void* d_out, int out_size, void* d_ws, size_t ws_size,
                              hipStream_t stream) {
    const float* pred = (const float*)d_in[0];
    const float* y    = (const float*)d_in[1];
    float* out        = (float*)d_out;
    float* partials   = (float*)d_ws;   // PBLK floats; each written exactly once

    tau_tri_kernel<<<PBLK, THR, 0, stream>>>(pred, y, partials);
    tau_finalize_kernel<<<1, PBLK, 0, stream>>>(partials, out);
}